// Round 3
// baseline (9433.011 us; speedup 1.0000x reference)
//
#include <hip/hip_runtime.h>
#include <stdint.h>

typedef unsigned short u16;
typedef unsigned int u32;
typedef short short8 __attribute__((ext_vector_type(8)));
typedef float f32x4 __attribute__((ext_vector_type(4)));
typedef float f32x2 __attribute__((ext_vector_type(2)));

#define T_STEPS 512
#define BATCH 64
#define IDIM 512
#define HDIM 1024
#define TBm (T_STEPS*BATCH)      /* 32768 */
#define N3 (3*HDIM)              /* 3072 */
#define NBLK 128                 /* scan blocks: 64 col-blocks x 2 row-halves */

// ---------------- helpers ----------------
__device__ __forceinline__ float bf2f(u16 s) {
  union { u32 u; float f; } v; v.u = ((u32)s) << 16; return v.f;
}
__device__ __forceinline__ u16 f2b(float f) {
  union { float f; u32 u; } v; v.f = f;
  u32 u = v.u;
  u += 0x7fffu + ((u >> 16) & 1u);   // RNE
  return (u16)(u >> 16);
}
__device__ __forceinline__ float ftanh(float x) {
  x = fminf(20.f, fmaxf(-20.f, x));
  float e = __expf(2.f * x);
  return (e - 1.f) / (e + 1.f);
}
__device__ __forceinline__ float fsigm(float x) {
  x = fminf(30.f, fmaxf(-30.f, x));
  return 1.f / (1.f + __expf(-x));
}

// ---------------- f32 -> (bf16 hi, bf16 lo) split, 4 elems/thread ----------------
__global__ void split_f32(const float* __restrict__ src, u16* __restrict__ hi,
                          u16* __restrict__ lo, int n4) {
  int i = blockIdx.x * blockDim.x + threadIdx.x;
  if (i >= n4) return;
  float4 a = ((const float4*)src)[i];
  u16 h0 = f2b(a.x), h1 = f2b(a.y), h2 = f2b(a.z), h3 = f2b(a.w);
  u16 l0 = f2b(a.x - bf2f(h0)), l1 = f2b(a.y - bf2f(h1));
  u16 l2 = f2b(a.z - bf2f(h2)), l3 = f2b(a.w - bf2f(h3));
  uint2 hv; hv.x = (u32)h0 | ((u32)h1 << 16); hv.y = (u32)h2 | ((u32)h3 << 16);
  uint2 lv; lv.x = (u32)l0 | ((u32)l1 << 16); lv.y = (u32)l2 | ((u32)l3 << 16);
  ((uint2*)hi)[i] = hv;
  ((uint2*)lo)[i] = lv;
}

// ---------------- ws-too-small sentinel ----------------
__global__ void ws_small_kernel(float* out, int n, float val) {
  int i = blockIdx.x * blockDim.x + threadIdx.x;
  for (; i < n; i += gridDim.x * blockDim.x) out[i] = val;
}

// ------------- projection GEMM (3-product split): P = Xh@Uh^T + Xh@Ul^T + Xl@Uh^T + b -------------
// Xh/Xl [TBm][512] bf16; Uh/Ul [3072][512] bf16. 128x128 tile, BK=32, 4 waves 2x2.
template<typename PT>
__global__ __launch_bounds__(256) void proj_gemm(const u16* __restrict__ Xh, const u16* __restrict__ Xl,
                                                 const u16* __restrict__ Uh, const u16* __restrict__ Ul,
                                                 const float* __restrict__ bias,
                                                 PT* __restrict__ Pb) {
  __shared__ u16 Ash[4096], Asl[4096], Bsh[4096], Bsl[4096];   // [kc=4][row=128][8]
  const int tid = threadIdx.x;
  const int bm = blockIdx.x, bn = blockIdx.y;
  const int w = tid >> 6, l = tid & 63;
  const int wm = w >> 1, wn = w & 1;
  const int lr = l & 15, kg = l >> 4;

  const int r0t = tid >> 2;           // 0..63
  const int kc = tid & 3;             // k-chunk 0..3
  const size_t ga0 = (size_t)(bm * 128 + r0t) * IDIM + kc * 8;
  const size_t ga1 = ga0 + (size_t)64 * IDIM;
  const size_t gb0 = (size_t)(bn * 128 + r0t) * IDIM + kc * 8;
  const size_t gb1 = gb0 + (size_t)64 * IDIM;
  const int la0 = (kc * 128 + r0t) * 8;
  const int la1 = la0 + 64 * 8;

  uint4 rah0 = *(const uint4*)(Xh + ga0);
  uint4 rah1 = *(const uint4*)(Xh + ga1);
  uint4 ral0 = *(const uint4*)(Xl + ga0);
  uint4 ral1 = *(const uint4*)(Xl + ga1);
  uint4 rbh0 = *(const uint4*)(Uh + gb0);
  uint4 rbh1 = *(const uint4*)(Uh + gb1);
  uint4 rbl0 = *(const uint4*)(Ul + gb0);
  uint4 rbl1 = *(const uint4*)(Ul + gb1);

  const f32x4 vz = {0.f, 0.f, 0.f, 0.f};
  f32x4 acc[4][4];
#pragma unroll
  for (int i = 0; i < 4; i++)
#pragma unroll
    for (int j = 0; j < 4; j++) acc[i][j] = vz;

  for (int kt = 0; kt < 16; kt++) {
    *(uint4*)&Ash[la0] = rah0; *(uint4*)&Ash[la1] = rah1;
    *(uint4*)&Asl[la0] = ral0; *(uint4*)&Asl[la1] = ral1;
    *(uint4*)&Bsh[la0] = rbh0; *(uint4*)&Bsh[la1] = rbh1;
    *(uint4*)&Bsl[la0] = rbl0; *(uint4*)&Bsl[la1] = rbl1;
    __syncthreads();
    if (kt < 15) {
      size_t ko = (size_t)(kt + 1) * 32;
      rah0 = *(const uint4*)(Xh + ga0 + ko); rah1 = *(const uint4*)(Xh + ga1 + ko);
      ral0 = *(const uint4*)(Xl + ga0 + ko); ral1 = *(const uint4*)(Xl + ga1 + ko);
      rbh0 = *(const uint4*)(Uh + gb0 + ko); rbh1 = *(const uint4*)(Uh + gb1 + ko);
      rbl0 = *(const uint4*)(Ul + gb0 + ko); rbl1 = *(const uint4*)(Ul + gb1 + ko);
    }
    short8 afh[4], afl[4], bfh[4], bfl[4];
#pragma unroll
    for (int mt = 0; mt < 4; mt++) {
      int idx = (kg * 128 + wm * 64 + mt * 16 + lr) * 8;
      afh[mt] = *(const short8*)&Ash[idx];
      afl[mt] = *(const short8*)&Asl[idx];
    }
#pragma unroll
    for (int nt = 0; nt < 4; nt++) {
      int idx = (kg * 128 + wn * 64 + nt * 16 + lr) * 8;
      bfh[nt] = *(const short8*)&Bsh[idx];
      bfl[nt] = *(const short8*)&Bsl[idx];
    }
#pragma unroll
    for (int mt = 0; mt < 4; mt++)
#pragma unroll
      for (int nt = 0; nt < 4; nt++) {
        acc[mt][nt] = __builtin_amdgcn_mfma_f32_16x16x32_bf16(afh[mt], bfh[nt], acc[mt][nt], 0, 0, 0);
        acc[mt][nt] = __builtin_amdgcn_mfma_f32_16x16x32_bf16(afh[mt], bfl[nt], acc[mt][nt], 0, 0, 0);
        acc[mt][nt] = __builtin_amdgcn_mfma_f32_16x16x32_bf16(afl[mt], bfh[nt], acc[mt][nt], 0, 0, 0);
      }
    __syncthreads();
  }
#pragma unroll
  for (int mt = 0; mt < 4; mt++) {
#pragma unroll
    for (int nt = 0; nt < 4; nt++) {
      int col = bn * 128 + wn * 64 + nt * 16 + lr;
      float bv = bias[col];
#pragma unroll
      for (int r = 0; r < 4; r++) {
        int row = bm * 128 + wm * 64 + mt * 16 + kg * 4 + r;
        Pb[(size_t)row * N3 + col] = (PT)(acc[mt][nt][r] + bv);
      }
    }
  }
}

// ---------------- persistent recurrent scan (3-chain split precision) ----------------
// 128 blocks x 256 thr. Block = (rh = blk>>6 row-half of 32, cb = blk&63 col-block of 16, both mats).
// Wave (mat = w>>1, kh = w&1): 32 rows x 16 cols, K-half 512, chains hh@Wh + hh@Wl + hl@Wh.
template<typename PT>
__global__ __launch_bounds__(256, 1) void scan_kernel(const PT* __restrict__ P,
                                                      const u16* __restrict__ Wh,
                                                      const u16* __restrict__ Wl,
                                                      const float* __restrict__ h0,
                                                      u16* __restrict__ Hh, u16* __restrict__ Hl,
                                                      u32* __restrict__ flags,
                                                      float* __restrict__ out) {
  __shared__ float ex[2][2][32][17];   // [mat][kh][row][col] (+1 pad)
  const int tid = threadIdx.x;
  const int blk = blockIdx.x;
  const int cb = blk & 63, rh = blk >> 6;
  const int c0 = cb * 16, r0 = rh * 32;
  const int w = tid >> 6, l = tid & 63;
  const int mat = w >> 1, kh = w & 1;
  const int lr = l & 15, lk = l >> 4;

  // W fragments -> VGPRs, held across all 512 steps (16 cols x 512 K per wave, hi+lo)
  short8 bwh[16], bwl[16];
  {
    const size_t woff = ((size_t)mat << 20) + (size_t)(c0 + lr) * HDIM + kh * 512 + lk * 8;
    const u16* bh = Wh + woff;
    const u16* bl = Wl + woff;
#pragma unroll
    for (int s = 0; s < 16; s++) {
      bwh[s] = *(const short8*)(bh + s * 32);
      bwl[s] = *(const short8*)(bl + s * 32);
    }
  }

  // elementwise ownership: thread -> (row er of 32, cols cg*2, cg*2+1 of 16); exact f32 state
  const int er = tid >> 3;            // 0..31
  const int cg = tid & 7;             // 0..7
  const int gr = r0 + er;             // global batch row
  const int gc = c0 + cg * 2;         // global col (even)
  float hs0 = h0[(size_t)gr * HDIM + gc];
  float hs1 = h0[(size_t)gr * HDIM + gc + 1];

  const f32x4 vz = {0.f, 0.f, 0.f, 0.f};
  u32 budget = 1u << 24;

#pragma unroll 1
  for (int t = 0; t < T_STEPS; t++) {
    // prefetch this step's projections (independent of h)
    const PT* prow = P + (size_t)(t * BATCH + gr) * N3 + gc;
    float xc0 = (float)prow[0],        xc1 = (float)prow[1];
    float xa0 = (float)prow[HDIM],     xa1 = (float)prow[HDIM + 1];
    float xh0 = (float)prow[2 * HDIM], xh1 = (float)prow[2 * HDIM + 1];

    if (t > 0) {
      if (tid < NBLK) {
        while (__hip_atomic_load(&flags[(size_t)t * NBLK + tid], __ATOMIC_RELAXED,
                                 __HIP_MEMORY_SCOPE_AGENT) == 0u) {
          if (--budget == 0u) break;
        }
      }
      __syncthreads();
      __builtin_amdgcn_fence(__ATOMIC_ACQUIRE, "agent");
    }

    const size_t hoff = (size_t)(t & 1) * BATCH * HDIM + (size_t)(r0 + lr) * HDIM + kh * 512 + lk * 8;
    const u16* ah0 = Hh + hoff;
    const u16* ah1 = ah0 + (size_t)16 * HDIM;
    const u16* al0 = Hl + hoff;
    const u16* al1 = al0 + (size_t)16 * HDIM;

    f32x4 a0e = vz, a0o = vz, a1e = vz, a1o = vz;
#pragma unroll
    for (int s = 0; s < 16; s += 2) {
      short8 vh0 = *(const short8*)(ah0 + s * 32);
      short8 vh1 = *(const short8*)(ah1 + s * 32);
      short8 vl0 = *(const short8*)(al0 + s * 32);
      short8 vl1 = *(const short8*)(al1 + s * 32);
      a0e = __builtin_amdgcn_mfma_f32_16x16x32_bf16(vh0, bwh[s], a0e, 0, 0, 0);
      a1e = __builtin_amdgcn_mfma_f32_16x16x32_bf16(vh1, bwh[s], a1e, 0, 0, 0);
      a0e = __builtin_amdgcn_mfma_f32_16x16x32_bf16(vh0, bwl[s], a0e, 0, 0, 0);
      a1e = __builtin_amdgcn_mfma_f32_16x16x32_bf16(vh1, bwl[s], a1e, 0, 0, 0);
      a0e = __builtin_amdgcn_mfma_f32_16x16x32_bf16(vl0, bwh[s], a0e, 0, 0, 0);
      a1e = __builtin_amdgcn_mfma_f32_16x16x32_bf16(vl1, bwh[s], a1e, 0, 0, 0);
      short8 wh0 = *(const short8*)(ah0 + (s + 1) * 32);
      short8 wh1 = *(const short8*)(ah1 + (s + 1) * 32);
      short8 wl0 = *(const short8*)(al0 + (s + 1) * 32);
      short8 wl1 = *(const short8*)(al1 + (s + 1) * 32);
      a0o = __builtin_amdgcn_mfma_f32_16x16x32_bf16(wh0, bwh[s + 1], a0o, 0, 0, 0);
      a1o = __builtin_amdgcn_mfma_f32_16x16x32_bf16(wh1, bwh[s + 1], a1o, 0, 0, 0);
      a0o = __builtin_amdgcn_mfma_f32_16x16x32_bf16(wh0, bwl[s + 1], a0o, 0, 0, 0);
      a1o = __builtin_amdgcn_mfma_f32_16x16x32_bf16(wh1, bwl[s + 1], a1o, 0, 0, 0);
      a0o = __builtin_amdgcn_mfma_f32_16x16x32_bf16(wl0, bwh[s + 1], a0o, 0, 0, 0);
      a1o = __builtin_amdgcn_mfma_f32_16x16x32_bf16(wl1, bwh[s + 1], a1o, 0, 0, 0);
    }
    f32x4 a0 = a0e + a0o;
    f32x4 a1 = a1e + a1o;

    // scatter pre-activation partials (D: col=l&15, row=(l>>4)*4+r)
#pragma unroll
    for (int r = 0; r < 4; r++) {
      ex[mat][kh][lk * 4 + r][lr] = a0[r];
      ex[mat][kh][16 + lk * 4 + r][lr] = a1[r];
    }
    __syncthreads();

    int cc = cg * 2;
    float cp0 = ex[0][0][er][cc] + ex[0][1][er][cc] + xc0;
    float cp1 = ex[0][0][er][cc + 1] + ex[0][1][er][cc + 1] + xc1;
    float ap0 = ex[1][0][er][cc] + ex[1][1][er][cc] + xa0;
    float ap1 = ex[1][0][er][cc + 1] + ex[1][1][er][cc + 1] + xa1;
    float c0g = fsigm(cp0), c1g = fsigm(cp1);
    float aa0 = 1.f + ftanh(ap0), aa1 = 1.f + ftanh(ap1);
    float th0 = ftanh(xh0 + aa0 * hs0), th1 = ftanh(xh1 + aa1 * hs1);
    float hn0 = c0g * hs0 + (1.f - c0g) * th0;
    float hn1 = c1g * hs1 + (1.f - c1g) * th1;
    hs0 = hn0; hs1 = hn1;

    // y output (f32)
    float* yrow = out + (size_t)t * BATCH * HDIM + (size_t)gr * HDIM + gc;
    f32x2 y = {hn0, hn1};
    __builtin_nontemporal_store(y, (f32x2*)yrow);
    if (t == T_STEPS - 1) {
      float* frow = out + (size_t)T_STEPS * BATCH * HDIM + (size_t)gr * HDIM + gc;
      __builtin_nontemporal_store(y, (f32x2*)frow);
    }

    // h_{t+1} hi/lo bf16, agent-scope stores
    u16 hb0 = f2b(hn0), hb1 = f2b(hn1);
    u16 lb0 = f2b(hn0 - bf2f(hb0)), lb1 = f2b(hn1 - bf2f(hb1));
    size_t hidx = ((size_t)((t + 1) & 1) * BATCH * HDIM + (size_t)gr * HDIM + gc) >> 1;
    __hip_atomic_store((u32*)Hh + hidx, (u32)hb0 | ((u32)hb1 << 16),
                       __ATOMIC_RELAXED, __HIP_MEMORY_SCOPE_AGENT);
    __hip_atomic_store((u32*)Hl + hidx, (u32)lb0 | ((u32)lb1 << 16),
                       __ATOMIC_RELAXED, __HIP_MEMORY_SCOPE_AGENT);

    __syncthreads();   // barrier drains vmcnt: all stores of this block complete
    if (tid == 0) {
      __builtin_amdgcn_fence(__ATOMIC_RELEASE, "agent");
      __hip_atomic_store(&flags[(size_t)(t + 1) * NBLK + blk], 1u,
                         __ATOMIC_RELAXED, __HIP_MEMORY_SCOPE_AGENT);
    }
  }
}

// ---------------- launcher ----------------
static const size_t SZ_X1 = (size_t)TBm * IDIM * 2;      // 32 MB (hi or lo)
static const size_t SZ_U1 = (size_t)N3 * IDIM * 2;       // 3 MB
static const size_t SZ_W1 = (size_t)2 * HDIM * HDIM * 2; // 4 MB
static const size_t SZ_B  = (size_t)N3 * 4;
static const size_t SZ_H1 = (size_t)2 * BATCH * HDIM * 2;
static const size_t SZ_F  = (size_t)(T_STEPS + 1) * NBLK * 4;
static const size_t SZ_TAIL = 2*SZ_X1 + 2*SZ_U1 + 2*SZ_W1 + SZ_B + 2*SZ_H1 + SZ_F;

template<typename PT>
static void launch_path(void* const* d_in, float* out, char* ws, hipStream_t stream) {
  const float* x_seq = (const float*)d_in[0];
  const float* h0   = (const float*)d_in[1];
  const float* U_c  = (const float*)d_in[2];
  const float* W_c  = (const float*)d_in[3];
  const float* b_c  = (const float*)d_in[4];
  const float* U_a  = (const float*)d_in[5];
  const float* W_a  = (const float*)d_in[6];
  const float* b_a  = (const float*)d_in[7];
  const float* U_h  = (const float*)d_in[8];
  const float* b_h  = (const float*)d_in[9];

  const size_t szP = (size_t)TBm * N3 * sizeof(PT);
  PT*  Pb  = (PT*)(ws);
  u16* Xh  = (u16*)(ws + szP);
  u16* Xl  = (u16*)(ws + szP + SZ_X1);
  u16* Uh  = (u16*)(ws + szP + 2*SZ_X1);
  u16* Ul  = (u16*)(ws + szP + 2*SZ_X1 + SZ_U1);
  u16* Wh  = (u16*)(ws + szP + 2*SZ_X1 + 2*SZ_U1);
  u16* Wl  = (u16*)(ws + szP + 2*SZ_X1 + 2*SZ_U1 + SZ_W1);
  float* bias = (float*)(ws + szP + 2*SZ_X1 + 2*SZ_U1 + 2*SZ_W1);
  u16* Hh  = (u16*)((char*)bias + SZ_B);
  u16* Hl  = (u16*)((char*)bias + SZ_B + SZ_H1);
  u32* Fl  = (u32*)((char*)bias + SZ_B + 2*SZ_H1);

  (void)hipMemsetAsync(Fl, 0, SZ_F, stream);
  (void)hipMemcpyAsync(bias + 0 * HDIM, b_c, HDIM * sizeof(float), hipMemcpyDeviceToDevice, stream);
  (void)hipMemcpyAsync(bias + 1 * HDIM, b_a, HDIM * sizeof(float), hipMemcpyDeviceToDevice, stream);
  (void)hipMemcpyAsync(bias + 2 * HDIM, b_h, HDIM * sizeof(float), hipMemcpyDeviceToDevice, stream);

  int n4;
  n4 = TBm * IDIM / 4;
  split_f32<<<(n4 + 255) / 256, 256, 0, stream>>>(x_seq, Xh, Xl, n4);
  n4 = HDIM * IDIM / 4;
  split_f32<<<(n4 + 255) / 256, 256, 0, stream>>>(U_c, Uh + 0 * (size_t)HDIM * IDIM, Ul + 0 * (size_t)HDIM * IDIM, n4);
  split_f32<<<(n4 + 255) / 256, 256, 0, stream>>>(U_a, Uh + 1 * (size_t)HDIM * IDIM, Ul + 1 * (size_t)HDIM * IDIM, n4);
  split_f32<<<(n4 + 255) / 256, 256, 0, stream>>>(U_h, Uh + 2 * (size_t)HDIM * IDIM, Ul + 2 * (size_t)HDIM * IDIM, n4);
  n4 = HDIM * HDIM / 4;
  split_f32<<<(n4 + 255) / 256, 256, 0, stream>>>(W_c, Wh, Wl, n4);
  split_f32<<<(n4 + 255) / 256, 256, 0, stream>>>(W_a, Wh + (size_t)HDIM * HDIM, Wl + (size_t)HDIM * HDIM, n4);
  n4 = BATCH * HDIM / 4;
  split_f32<<<(n4 + 255) / 256, 256, 0, stream>>>(h0, Hh, Hl, n4);

  proj_gemm<PT><<<dim3(TBm / 128, N3 / 128), 256, 0, stream>>>(Xh, Xl, Uh, Ul, bias, Pb);
  scan_kernel<PT><<<NBLK, 256, 0, stream>>>(Pb, Wh, Wl, h0, Hh, Hl, Fl, out);
}

extern "C" void kernel_launch(void* const* d_in, const int* in_sizes, int n_in,
                              void* d_out, int out_size, void* d_ws, size_t ws_size,
                              hipStream_t stream) {
  const size_t need_f32 = (size_t)TBm * N3 * 4 + SZ_TAIL;   // ~463 MB
  const size_t need_f16 = (size_t)TBm * N3 * 2 + SZ_TAIL;   // ~271 MB

  if (ws_size >= need_f32) {
    launch_path<float>(d_in, (float*)d_out, (char*)d_ws, stream);
  } else if (ws_size >= need_f16) {
    launch_path<_Float16>(d_in, (float*)d_out, (char*)d_ws, stream);
  } else {
    float v = 1.0e6f + (float)(ws_size >> 20);   // sentinel: encodes ws MB
    ws_small_kernel<<<2048, 256, 0, stream>>>((float*)d_out, out_size, v);
  }
}

// Round 4
// 5204.746 us; speedup vs baseline: 1.8124x; 1.8124x over previous
//
#include <hip/hip_runtime.h>
#include <stdint.h>

typedef unsigned short u16;
typedef unsigned int u32;
typedef unsigned long long u64;
typedef short short8 __attribute__((ext_vector_type(8)));
typedef float f32x4 __attribute__((ext_vector_type(4)));
typedef float f32x2 __attribute__((ext_vector_type(2)));

#define T_STEPS 512
#define BATCH 64
#define IDIM 512
#define HDIM 1024
#define TBm (T_STEPS*BATCH)      /* 32768 */
#define N3 (3*HDIM)              /* 3072 */
#define NBLK 128                 /* scan blocks: 64 col-blocks x 2 row-halves */

// ---------------- helpers ----------------
__device__ __forceinline__ float bf2f(u16 s) {
  union { u32 u; float f; } v; v.u = ((u32)s) << 16; return v.f;
}
__device__ __forceinline__ u16 f2b(float f) {
  union { float f; u32 u; } v; v.f = f;
  u32 u = v.u;
  u += 0x7fffu + ((u >> 16) & 1u);   // RNE
  return (u16)(u >> 16);
}
__device__ __forceinline__ float ftanh(float x) {
  x = fminf(20.f, fmaxf(-20.f, x));
  float e = __expf(2.f * x);
  return (e - 1.f) / (e + 1.f);
}
__device__ __forceinline__ float fsigm(float x) {
  x = fminf(30.f, fmaxf(-30.f, x));
  return 1.f / (1.f + __expf(-x));
}
__device__ __forceinline__ u64 aload(const u16* p) {
  return __hip_atomic_load((const u64*)p, __ATOMIC_RELAXED, __HIP_MEMORY_SCOPE_AGENT);
}

// ---------------- f32 -> (bf16 hi, bf16 lo) split, 4 elems/thread ----------------
__global__ void split_f32(const float* __restrict__ src, u16* __restrict__ hi,
                          u16* __restrict__ lo, int n4) {
  int i = blockIdx.x * blockDim.x + threadIdx.x;
  if (i >= n4) return;
  float4 a = ((const float4*)src)[i];
  u16 h0 = f2b(a.x), h1 = f2b(a.y), h2 = f2b(a.z), h3 = f2b(a.w);
  u16 l0 = f2b(a.x - bf2f(h0)), l1 = f2b(a.y - bf2f(h1));
  u16 l2 = f2b(a.z - bf2f(h2)), l3 = f2b(a.w - bf2f(h3));
  uint2 hv; hv.x = (u32)h0 | ((u32)h1 << 16); hv.y = (u32)h2 | ((u32)h3 << 16);
  uint2 lv; lv.x = (u32)l0 | ((u32)l1 << 16); lv.y = (u32)l2 | ((u32)l3 << 16);
  ((uint2*)hi)[i] = hv;
  ((uint2*)lo)[i] = lv;
}

// ---------------- ws-too-small sentinel ----------------
__global__ void ws_small_kernel(float* out, int n, float val) {
  int i = blockIdx.x * blockDim.x + threadIdx.x;
  for (; i < n; i += gridDim.x * blockDim.x) out[i] = val;
}

// ------------- projection GEMM (3-product split): P = Xh@Uh^T + Xh@Ul^T + Xl@Uh^T + b -------------
template<typename PT>
__global__ __launch_bounds__(256) void proj_gemm(const u16* __restrict__ Xh, const u16* __restrict__ Xl,
                                                 const u16* __restrict__ Uh, const u16* __restrict__ Ul,
                                                 const float* __restrict__ bias,
                                                 PT* __restrict__ Pb) {
  __shared__ u16 Ash[4096], Asl[4096], Bsh[4096], Bsl[4096];   // [kc=4][row=128][8]
  const int tid = threadIdx.x;
  const int bm = blockIdx.x, bn = blockIdx.y;
  const int w = tid >> 6, l = tid & 63;
  const int wm = w >> 1, wn = w & 1;
  const int lr = l & 15, kg = l >> 4;

  const int r0t = tid >> 2;           // 0..63
  const int kc = tid & 3;             // k-chunk 0..3
  const size_t ga0 = (size_t)(bm * 128 + r0t) * IDIM + kc * 8;
  const size_t ga1 = ga0 + (size_t)64 * IDIM;
  const size_t gb0 = (size_t)(bn * 128 + r0t) * IDIM + kc * 8;
  const size_t gb1 = gb0 + (size_t)64 * IDIM;
  const int la0 = (kc * 128 + r0t) * 8;
  const int la1 = la0 + 64 * 8;

  uint4 rah0 = *(const uint4*)(Xh + ga0);
  uint4 rah1 = *(const uint4*)(Xh + ga1);
  uint4 ral0 = *(const uint4*)(Xl + ga0);
  uint4 ral1 = *(const uint4*)(Xl + ga1);
  uint4 rbh0 = *(const uint4*)(Uh + gb0);
  uint4 rbh1 = *(const uint4*)(Uh + gb1);
  uint4 rbl0 = *(const uint4*)(Ul + gb0);
  uint4 rbl1 = *(const uint4*)(Ul + gb1);

  const f32x4 vz = {0.f, 0.f, 0.f, 0.f};
  f32x4 acc[4][4];
#pragma unroll
  for (int i = 0; i < 4; i++)
#pragma unroll
    for (int j = 0; j < 4; j++) acc[i][j] = vz;

  for (int kt = 0; kt < 16; kt++) {
    *(uint4*)&Ash[la0] = rah0; *(uint4*)&Ash[la1] = rah1;
    *(uint4*)&Asl[la0] = ral0; *(uint4*)&Asl[la1] = ral1;
    *(uint4*)&Bsh[la0] = rbh0; *(uint4*)&Bsh[la1] = rbh1;
    *(uint4*)&Bsl[la0] = rbl0; *(uint4*)&Bsl[la1] = rbl1;
    __syncthreads();
    if (kt < 15) {
      size_t ko = (size_t)(kt + 1) * 32;
      rah0 = *(const uint4*)(Xh + ga0 + ko); rah1 = *(const uint4*)(Xh + ga1 + ko);
      ral0 = *(const uint4*)(Xl + ga0 + ko); ral1 = *(const uint4*)(Xl + ga1 + ko);
      rbh0 = *(const uint4*)(Uh + gb0 + ko); rbh1 = *(const uint4*)(Uh + gb1 + ko);
      rbl0 = *(const uint4*)(Ul + gb0 + ko); rbl1 = *(const uint4*)(Ul + gb1 + ko);
    }
    short8 afh[4], afl[4], bfh[4], bfl[4];
#pragma unroll
    for (int mt = 0; mt < 4; mt++) {
      int idx = (kg * 128 + wm * 64 + mt * 16 + lr) * 8;
      afh[mt] = *(const short8*)&Ash[idx];
      afl[mt] = *(const short8*)&Asl[idx];
    }
#pragma unroll
    for (int nt = 0; nt < 4; nt++) {
      int idx = (kg * 128 + wn * 64 + nt * 16 + lr) * 8;
      bfh[nt] = *(const short8*)&Bsh[idx];
      bfl[nt] = *(const short8*)&Bsl[idx];
    }
#pragma unroll
    for (int mt = 0; mt < 4; mt++)
#pragma unroll
      for (int nt = 0; nt < 4; nt++) {
        acc[mt][nt] = __builtin_amdgcn_mfma_f32_16x16x32_bf16(afh[mt], bfh[nt], acc[mt][nt], 0, 0, 0);
        acc[mt][nt] = __builtin_amdgcn_mfma_f32_16x16x32_bf16(afh[mt], bfl[nt], acc[mt][nt], 0, 0, 0);
        acc[mt][nt] = __builtin_amdgcn_mfma_f32_16x16x32_bf16(afl[mt], bfh[nt], acc[mt][nt], 0, 0, 0);
      }
    __syncthreads();
  }
#pragma unroll
  for (int mt = 0; mt < 4; mt++) {
#pragma unroll
    for (int nt = 0; nt < 4; nt++) {
      int col = bn * 128 + wn * 64 + nt * 16 + lr;
      float bv = bias[col];
#pragma unroll
      for (int r = 0; r < 4; r++) {
        int row = bm * 128 + wm * 64 + mt * 16 + kg * 4 + r;
        Pb[(size_t)row * N3 + col] = (PT)(acc[mt][nt][r] + bv);
      }
    }
  }
}

// ---------------- persistent recurrent scan (fence-free, atomic data path) ----------------
// 128 blocks x 512 thr (8 waves). Block = (rh = blk>>6: 32 rows, cb = blk&63: 16 cols, BOTH mats).
// Wave w = K-eighth (128 K-lanes), covers both mats: W frags = 2 mats x 4 ktiles x hi/lo = 64 VGPRs.
// Cross-block h exchange: agent-scope atomic u64 loads/stores only (IC-coherent), NO fences.
template<typename PT>
__global__ __launch_bounds__(512, 1) void scan_kernel(const PT* __restrict__ P,
                                                      const u16* __restrict__ Wh,
                                                      const u16* __restrict__ Wl,
                                                      const float* __restrict__ h0,
                                                      u16* __restrict__ Hh, u16* __restrict__ Hl,
                                                      u32* __restrict__ flags,
                                                      float* __restrict__ out) {
  __shared__ float ex[2][8][32][17];   // [mat][kq][row][col] (+1 pad)
  const int tid = threadIdx.x;
  const int blk = blockIdx.x;
  const int cb = blk & 63, rh = blk >> 6;
  const int c0 = cb * 16, r0 = rh * 32;
  const int w = tid >> 6, l = tid & 63;   // w = K-eighth
  const int lr = l & 15, lk = l >> 4;

  // W fragments -> VGPRs (64 regs), held across all 512 steps
  short8 bwh[2][4], bwl[2][4];
#pragma unroll
  for (int m = 0; m < 2; m++) {
    const size_t woff = ((size_t)m << 20) + (size_t)(c0 + lr) * HDIM + w * 128 + lk * 8;
#pragma unroll
    for (int s = 0; s < 4; s++) {
      bwh[m][s] = *(const short8*)(Wh + woff + s * 32);
      bwl[m][s] = *(const short8*)(Wl + woff + s * 32);
    }
  }

  // elementwise ownership (tid<256): thread -> (row er of 32, col pair); exact f32 state
  const int er = (tid & 255) >> 3;       // 0..31
  const int cq = tid & 7;                // 0..7
  const int gr = r0 + er;
  const int gc = c0 + cq * 2;
  float hs0 = 0.f, hs1 = 0.f;
  if (tid < 256) {
    hs0 = h0[(size_t)gr * HDIM + gc];
    hs1 = h0[(size_t)gr * HDIM + gc + 1];
  }

  const f32x4 vz = {0.f, 0.f, 0.f, 0.f};
  u32 budget = 1u << 24;

#pragma unroll 1
  for (int t = 0; t < T_STEPS; t++) {
    // prefetch this step's projections (independent of h; overlaps spin-wait)
    float xc0 = 0.f, xc1 = 0.f, xa0 = 0.f, xa1 = 0.f, xh0 = 0.f, xh1 = 0.f;
    if (tid < 256) {
      const PT* prow = P + (size_t)(t * BATCH + gr) * N3 + gc;
      xc0 = (float)prow[0];        xc1 = (float)prow[1];
      xa0 = (float)prow[HDIM];     xa1 = (float)prow[HDIM + 1];
      xh0 = (float)prow[2 * HDIM]; xh1 = (float)prow[2 * HDIM + 1];
    }

    if (t > 0) {
      if (tid < NBLK) {
        while (__hip_atomic_load(&flags[(size_t)t * NBLK + tid], __ATOMIC_RELAXED,
                                 __HIP_MEMORY_SCOPE_AGENT) == 0u) {
          if (--budget == 0u) break;
        }
      }
      __syncthreads();
    }

    // h fragments via IC-coherent atomic loads; MFMA 3-chain, both mats
    const size_t hb = (size_t)(t & 1) * BATCH * HDIM;
    f32x4 acc[2][2];   // [mat][rowtile]
    acc[0][0] = vz; acc[0][1] = vz; acc[1][0] = vz; acc[1][1] = vz;
#pragma unroll
    for (int rt = 0; rt < 2; rt++) {
      const size_t off = hb + (size_t)(r0 + rt * 16 + lr) * HDIM + w * 128 + lk * 8;
#pragma unroll
      for (int s = 0; s < 4; s++) {
        union { u64 q[2]; short8 v; } vh, vl;
        vh.q[0] = aload(Hh + off + s * 32);
        vh.q[1] = aload(Hh + off + s * 32 + 4);
        vl.q[0] = aload(Hl + off + s * 32);
        vl.q[1] = aload(Hl + off + s * 32 + 4);
        acc[0][rt] = __builtin_amdgcn_mfma_f32_16x16x32_bf16(vh.v, bwh[0][s], acc[0][rt], 0, 0, 0);
        acc[0][rt] = __builtin_amdgcn_mfma_f32_16x16x32_bf16(vh.v, bwl[0][s], acc[0][rt], 0, 0, 0);
        acc[0][rt] = __builtin_amdgcn_mfma_f32_16x16x32_bf16(vl.v, bwh[0][s], acc[0][rt], 0, 0, 0);
        acc[1][rt] = __builtin_amdgcn_mfma_f32_16x16x32_bf16(vh.v, bwh[1][s], acc[1][rt], 0, 0, 0);
        acc[1][rt] = __builtin_amdgcn_mfma_f32_16x16x32_bf16(vh.v, bwl[1][s], acc[1][rt], 0, 0, 0);
        acc[1][rt] = __builtin_amdgcn_mfma_f32_16x16x32_bf16(vl.v, bwh[1][s], acc[1][rt], 0, 0, 0);
      }
    }

    // scatter partial pre-activations (D: col=l&15, row=(l>>4)*4+r)
#pragma unroll
    for (int m = 0; m < 2; m++)
#pragma unroll
      for (int rt = 0; rt < 2; rt++)
#pragma unroll
        for (int r = 0; r < 4; r++)
          ex[m][w][rt * 16 + lk * 4 + r][lr] = acc[m][rt][r];
    __syncthreads();

    float hn0 = 0.f, hn1 = 0.f;
    if (tid < 256) {
      const int ec = cq * 2;
      float cp0 = xc0, cp1 = xc1, ap0 = xa0, ap1 = xa1;
#pragma unroll
      for (int q = 0; q < 8; q++) {
        cp0 += ex[0][q][er][ec];     cp1 += ex[0][q][er][ec + 1];
        ap0 += ex[1][q][er][ec];     ap1 += ex[1][q][er][ec + 1];
      }
      float c0g = fsigm(cp0), c1g = fsigm(cp1);
      float aa0 = 1.f + ftanh(ap0), aa1 = 1.f + ftanh(ap1);
      float th0 = ftanh(xh0 + aa0 * hs0), th1 = ftanh(xh1 + aa1 * hs1);
      hn0 = c0g * hs0 + (1.f - c0g) * th0;
      hn1 = c1g * hs1 + (1.f - c1g) * th1;
      hs0 = hn0; hs1 = hn1;

      // h_{t+1} hi/lo bf16 -> IC via agent-scope atomic stores
      u16 hb0 = f2b(hn0), hb1 = f2b(hn1);
      u16 lb0 = f2b(hn0 - bf2f(hb0)), lb1 = f2b(hn1 - bf2f(hb1));
      size_t hidx = ((size_t)((t + 1) & 1) * BATCH * HDIM + (size_t)gr * HDIM + gc) >> 1;
      __hip_atomic_store((u32*)Hh + hidx, (u32)hb0 | ((u32)hb1 << 16),
                         __ATOMIC_RELAXED, __HIP_MEMORY_SCOPE_AGENT);
      __hip_atomic_store((u32*)Hl + hidx, (u32)lb0 | ((u32)lb1 << 16),
                         __ATOMIC_RELAXED, __HIP_MEMORY_SCOPE_AGENT);
    }

    __syncthreads();   // vmcnt(0) drain: h stores ack'd at coherent point
    if (tid == 0)
      __hip_atomic_store(&flags[(size_t)(t + 1) * NBLK + blk], 1u,
                         __ATOMIC_RELAXED, __HIP_MEMORY_SCOPE_AGENT);

    // y stores AFTER the flag (off the inter-block critical path)
    if (tid < 256) {
      float* yrow = out + (size_t)t * BATCH * HDIM + (size_t)gr * HDIM + gc;
      f32x2 y = {hn0, hn1};
      __builtin_nontemporal_store(y, (f32x2*)yrow);
      if (t == T_STEPS - 1) {
        float* frow = out + (size_t)T_STEPS * BATCH * HDIM + (size_t)gr * HDIM + gc;
        __builtin_nontemporal_store(y, (f32x2*)frow);
      }
    }
  }
}

// ---------------- launcher ----------------
static const size_t SZ_X1 = (size_t)TBm * IDIM * 2;      // 32 MB (hi or lo)
static const size_t SZ_U1 = (size_t)N3 * IDIM * 2;       // 3 MB
static const size_t SZ_W1 = (size_t)2 * HDIM * HDIM * 2; // 4 MB
static const size_t SZ_B  = (size_t)N3 * 4;
static const size_t SZ_H1 = (size_t)2 * BATCH * HDIM * 2;
static const size_t SZ_F  = (size_t)(T_STEPS + 1) * NBLK * 4;
static const size_t SZ_TAIL = 2*SZ_X1 + 2*SZ_U1 + 2*SZ_W1 + SZ_B + 2*SZ_H1 + SZ_F;

template<typename PT>
static void launch_path(void* const* d_in, float* out, char* ws, hipStream_t stream) {
  const float* x_seq = (const float*)d_in[0];
  const float* h0   = (const float*)d_in[1];
  const float* U_c  = (const float*)d_in[2];
  const float* W_c  = (const float*)d_in[3];
  const float* b_c  = (const float*)d_in[4];
  const float* U_a  = (const float*)d_in[5];
  const float* W_a  = (const float*)d_in[6];
  const float* b_a  = (const float*)d_in[7];
  const float* U_h  = (const float*)d_in[8];
  const float* b_h  = (const float*)d_in[9];

  const size_t szP = (size_t)TBm * N3 * sizeof(PT);
  PT*  Pb  = (PT*)(ws);
  u16* Xh  = (u16*)(ws + szP);
  u16* Xl  = (u16*)(ws + szP + SZ_X1);
  u16* Uh  = (u16*)(ws + szP + 2*SZ_X1);
  u16* Ul  = (u16*)(ws + szP + 2*SZ_X1 + SZ_U1);
  u16* Wh  = (u16*)(ws + szP + 2*SZ_X1 + 2*SZ_U1);
  u16* Wl  = (u16*)(ws + szP + 2*SZ_X1 + 2*SZ_U1 + SZ_W1);
  float* bias = (float*)(ws + szP + 2*SZ_X1 + 2*SZ_U1 + 2*SZ_W1);
  u16* Hh  = (u16*)((char*)bias + SZ_B);
  u16* Hl  = (u16*)((char*)bias + SZ_B + SZ_H1);
  u32* Fl  = (u32*)((char*)bias + SZ_B + 2*SZ_H1);

  (void)hipMemsetAsync(Fl, 0, SZ_F, stream);
  (void)hipMemcpyAsync(bias + 0 * HDIM, b_c, HDIM * sizeof(float), hipMemcpyDeviceToDevice, stream);
  (void)hipMemcpyAsync(bias + 1 * HDIM, b_a, HDIM * sizeof(float), hipMemcpyDeviceToDevice, stream);
  (void)hipMemcpyAsync(bias + 2 * HDIM, b_h, HDIM * sizeof(float), hipMemcpyDeviceToDevice, stream);

  int n4;
  n4 = TBm * IDIM / 4;
  split_f32<<<(n4 + 255) / 256, 256, 0, stream>>>(x_seq, Xh, Xl, n4);
  n4 = HDIM * IDIM / 4;
  split_f32<<<(n4 + 255) / 256, 256, 0, stream>>>(U_c, Uh + 0 * (size_t)HDIM * IDIM, Ul + 0 * (size_t)HDIM * IDIM, n4);
  split_f32<<<(n4 + 255) / 256, 256, 0, stream>>>(U_a, Uh + 1 * (size_t)HDIM * IDIM, Ul + 1 * (size_t)HDIM * IDIM, n4);
  split_f32<<<(n4 + 255) / 256, 256, 0, stream>>>(U_h, Uh + 2 * (size_t)HDIM * IDIM, Ul + 2 * (size_t)HDIM * IDIM, n4);
  n4 = HDIM * HDIM / 4;
  split_f32<<<(n4 + 255) / 256, 256, 0, stream>>>(W_c, Wh, Wl, n4);
  split_f32<<<(n4 + 255) / 256, 256, 0, stream>>>(W_a, Wh + (size_t)HDIM * HDIM, Wl + (size_t)HDIM * HDIM, n4);
  n4 = BATCH * HDIM / 4;
  split_f32<<<(n4 + 255) / 256, 256, 0, stream>>>(h0, Hh, Hl, n4);

  proj_gemm<PT><<<dim3(TBm / 128, N3 / 128), 256, 0, stream>>>(Xh, Xl, Uh, Ul, bias, Pb);
  scan_kernel<PT><<<NBLK, 512, 0, stream>>>(Pb, Wh, Wl, h0, Hh, Hl, Fl, out);
}

extern "C" void kernel_launch(void* const* d_in, const int* in_sizes, int n_in,
                              void* d_out, int out_size, void* d_ws, size_t ws_size,
                              hipStream_t stream) {
  const size_t need_f32 = (size_t)TBm * N3 * 4 + SZ_TAIL;   // ~463 MB
  const size_t need_f16 = (size_t)TBm * N3 * 2 + SZ_TAIL;   // ~271 MB

  if (ws_size >= need_f32) {
    launch_path<float>(d_in, (float*)d_out, (char*)d_ws, stream);
  } else if (ws_size >= need_f16) {
    launch_path<_Float16>(d_in, (float*)d_out, (char*)d_ws, stream);
  } else {
    float v = 1.0e6f + (float)(ws_size >> 20);   // sentinel: encodes ws MB
    ws_small_kernel<<<2048, 256, 0, stream>>>((float*)d_out, out_size, v);
  }
}

// Round 5
// 3519.695 us; speedup vs baseline: 2.6801x; 1.4787x over previous
//
#include <hip/hip_runtime.h>
#include <stdint.h>

typedef unsigned short u16;
typedef unsigned int u32;
typedef unsigned long long u64;
typedef short short8 __attribute__((ext_vector_type(8)));
typedef float f32x4 __attribute__((ext_vector_type(4)));
typedef float f32x2 __attribute__((ext_vector_type(2)));

#define T_STEPS 512
#define BATCH 64
#define IDIM 512
#define HDIM 1024
#define TBm (T_STEPS*BATCH)      /* 32768 */
#define N3 (3*HDIM)              /* 3072 */
#define NBLK 128                 /* scan blocks: 64 col-blocks x 2 row-halves */

// ---------------- helpers ----------------
__device__ __forceinline__ float bf2f(u16 s) {
  union { u32 u; float f; } v; v.u = ((u32)s) << 16; return v.f;
}
__device__ __forceinline__ u16 f2b(float f) {
  union { float f; u32 u; } v; v.f = f;
  u32 u = v.u;
  u += 0x7fffu + ((u >> 16) & 1u);   // RNE
  return (u16)(u >> 16);
}
__device__ __forceinline__ float ftanh(float x) {
  x = fminf(20.f, fmaxf(-20.f, x));
  float e = __expf(2.f * x);
  return (e - 1.f) / (e + 1.f);
}
__device__ __forceinline__ float fsigm(float x) {
  x = fminf(30.f, fmaxf(-30.f, x));
  return 1.f / (1.f + __expf(-x));
}

// ---------------- f32 -> (bf16 hi, bf16 lo) split, 4 elems/thread ----------------
__global__ void split_f32(const float* __restrict__ src, u16* __restrict__ hi,
                          u16* __restrict__ lo, int n4) {
  int i = blockIdx.x * blockDim.x + threadIdx.x;
  if (i >= n4) return;
  float4 a = ((const float4*)src)[i];
  u16 h0 = f2b(a.x), h1 = f2b(a.y), h2 = f2b(a.z), h3 = f2b(a.w);
  u16 l0 = f2b(a.x - bf2f(h0)), l1 = f2b(a.y - bf2f(h1));
  u16 l2 = f2b(a.z - bf2f(h2)), l3 = f2b(a.w - bf2f(h3));
  uint2 hv; hv.x = (u32)h0 | ((u32)h1 << 16); hv.y = (u32)h2 | ((u32)h3 << 16);
  uint2 lv; lv.x = (u32)l0 | ((u32)l1 << 16); lv.y = (u32)l2 | ((u32)l3 << 16);
  ((uint2*)hi)[i] = hv;
  ((uint2*)lo)[i] = lv;
}

// ---------------- ws-too-small sentinel ----------------
__global__ void ws_small_kernel(float* out, int n, float val) {
  int i = blockIdx.x * blockDim.x + threadIdx.x;
  for (; i < n; i += gridDim.x * blockDim.x) out[i] = val;
}

// ------------- projection GEMM (3-product split): P = Xh@Uh^T + Xh@Ul^T + Xl@Uh^T + b -------------
template<typename PT>
__global__ __launch_bounds__(256) void proj_gemm(const u16* __restrict__ Xh, const u16* __restrict__ Xl,
                                                 const u16* __restrict__ Uh, const u16* __restrict__ Ul,
                                                 const float* __restrict__ bias,
                                                 PT* __restrict__ Pb) {
  __shared__ u16 Ash[4096], Asl[4096], Bsh[4096], Bsl[4096];   // [kc=4][row=128][8]
  const int tid = threadIdx.x;
  const int bm = blockIdx.x, bn = blockIdx.y;
  const int w = tid >> 6, l = tid & 63;
  const int wm = w >> 1, wn = w & 1;
  const int lr = l & 15, kg = l >> 4;

  const int r0t = tid >> 2;           // 0..63
  const int kc = tid & 3;             // k-chunk 0..3
  const size_t ga0 = (size_t)(bm * 128 + r0t) * IDIM + kc * 8;
  const size_t ga1 = ga0 + (size_t)64 * IDIM;
  const size_t gb0 = (size_t)(bn * 128 + r0t) * IDIM + kc * 8;
  const size_t gb1 = gb0 + (size_t)64 * IDIM;
  const int la0 = (kc * 128 + r0t) * 8;
  const int la1 = la0 + 64 * 8;

  uint4 rah0 = *(const uint4*)(Xh + ga0);
  uint4 rah1 = *(const uint4*)(Xh + ga1);
  uint4 ral0 = *(const uint4*)(Xl + ga0);
  uint4 ral1 = *(const uint4*)(Xl + ga1);
  uint4 rbh0 = *(const uint4*)(Uh + gb0);
  uint4 rbh1 = *(const uint4*)(Uh + gb1);
  uint4 rbl0 = *(const uint4*)(Ul + gb0);
  uint4 rbl1 = *(const uint4*)(Ul + gb1);

  const f32x4 vz = {0.f, 0.f, 0.f, 0.f};
  f32x4 acc[4][4];
#pragma unroll
  for (int i = 0; i < 4; i++)
#pragma unroll
    for (int j = 0; j < 4; j++) acc[i][j] = vz;

  for (int kt = 0; kt < 16; kt++) {
    *(uint4*)&Ash[la0] = rah0; *(uint4*)&Ash[la1] = rah1;
    *(uint4*)&Asl[la0] = ral0; *(uint4*)&Asl[la1] = ral1;
    *(uint4*)&Bsh[la0] = rbh0; *(uint4*)&Bsh[la1] = rbh1;
    *(uint4*)&Bsl[la0] = rbl0; *(uint4*)&Bsl[la1] = rbl1;
    __syncthreads();
    if (kt < 15) {
      size_t ko = (size_t)(kt + 1) * 32;
      rah0 = *(const uint4*)(Xh + ga0 + ko); rah1 = *(const uint4*)(Xh + ga1 + ko);
      ral0 = *(const uint4*)(Xl + ga0 + ko); ral1 = *(const uint4*)(Xl + ga1 + ko);
      rbh0 = *(const uint4*)(Uh + gb0 + ko); rbh1 = *(const uint4*)(Uh + gb1 + ko);
      rbl0 = *(const uint4*)(Ul + gb0 + ko); rbl1 = *(const uint4*)(Ul + gb1 + ko);
    }
    short8 afh[4], afl[4], bfh[4], bfl[4];
#pragma unroll
    for (int mt = 0; mt < 4; mt++) {
      int idx = (kg * 128 + wm * 64 + mt * 16 + lr) * 8;
      afh[mt] = *(const short8*)&Ash[idx];
      afl[mt] = *(const short8*)&Asl[idx];
    }
#pragma unroll
    for (int nt = 0; nt < 4; nt++) {
      int idx = (kg * 128 + wn * 64 + nt * 16 + lr) * 8;
      bfh[nt] = *(const short8*)&Bsh[idx];
      bfl[nt] = *(const short8*)&Bsl[idx];
    }
#pragma unroll
    for (int mt = 0; mt < 4; mt++)
#pragma unroll
      for (int nt = 0; nt < 4; nt++) {
        acc[mt][nt] = __builtin_amdgcn_mfma_f32_16x16x32_bf16(afh[mt], bfh[nt], acc[mt][nt], 0, 0, 0);
        acc[mt][nt] = __builtin_amdgcn_mfma_f32_16x16x32_bf16(afh[mt], bfl[nt], acc[mt][nt], 0, 0, 0);
        acc[mt][nt] = __builtin_amdgcn_mfma_f32_16x16x32_bf16(afl[mt], bfh[nt], acc[mt][nt], 0, 0, 0);
      }
    __syncthreads();
  }
#pragma unroll
  for (int mt = 0; mt < 4; mt++) {
#pragma unroll
    for (int nt = 0; nt < 4; nt++) {
      int col = bn * 128 + wn * 64 + nt * 16 + lr;
      float bv = bias[col];
#pragma unroll
      for (int r = 0; r < 4; r++) {
        int row = bm * 128 + wm * 64 + mt * 16 + kg * 4 + r;
        Pb[(size_t)row * N3 + col] = (PT)(acc[mt][nt][r] + bv);
      }
    }
  }
}

// ---------------- persistent recurrent scan ----------------
// 128 blocks x 512 thr (8 waves). Block (rh = blk>>6: 32 rows, cb = blk&63: 16 cols, BOTH mats).
// Sync: per-(step,row-half) counter, 1 producer-add + 1 poller per block (s_sleep backoff).
// h data: agent-atomic u32 stores (reach IC pre-flag) + PLAIN sc0/sc1 bypass dwordx4 loads (full BW).
template<typename PT>
__global__ __launch_bounds__(512, 1) void scan_kernel(const PT* __restrict__ P,
                                                      const u16* __restrict__ Wh,
                                                      const u16* __restrict__ Wl,
                                                      const float* __restrict__ h0,
                                                      u16* __restrict__ Hh, u16* __restrict__ Hl,
                                                      u32* __restrict__ cnt,
                                                      float* __restrict__ out) {
  __shared__ float ex[2][8][32][17];   // [mat][kq][row][col] (+1 pad)
  const int tid = threadIdx.x;
  const int blk = blockIdx.x;
  const int cb = blk & 63, rh = blk >> 6;
  const int c0 = cb * 16, r0 = rh * 32;
  const int w = tid >> 6, l = tid & 63;   // w = K-eighth
  const int lr = l & 15, lk = l >> 4;

  // W fragments -> VGPRs (64 regs), held across all 512 steps
  short8 bwh[2][4], bwl[2][4];
#pragma unroll
  for (int m = 0; m < 2; m++) {
    const size_t woff = ((size_t)m << 20) + (size_t)(c0 + lr) * HDIM + w * 128 + lk * 8;
#pragma unroll
    for (int s = 0; s < 4; s++) {
      bwh[m][s] = *(const short8*)(Wh + woff + s * 32);
      bwl[m][s] = *(const short8*)(Wl + woff + s * 32);
    }
  }

  // elementwise ownership (tid<256): thread -> (row er of 32, col pair); exact f32 state
  const int er = (tid & 255) >> 3;       // 0..31
  const int cq = tid & 7;                // 0..7
  const int gr = r0 + er;
  const int gc = c0 + cq * 2;
  float hs0 = 0.f, hs1 = 0.f;
  if (tid < 256) {
    hs0 = h0[(size_t)gr * HDIM + gc];
    hs1 = h0[(size_t)gr * HDIM + gc + 1];
  }

  const f32x4 vz = {0.f, 0.f, 0.f, 0.f};
  u32 budget = 1u << 20;   // poll budget (anti-hang)

#pragma unroll 1
  for (int t = 0; t < T_STEPS; t++) {
    // prefetch this step's projections (independent of h; overlaps poll)
    float xc0 = 0.f, xc1 = 0.f, xa0 = 0.f, xa1 = 0.f, xh0 = 0.f, xh1 = 0.f;
    if (tid < 256) {
      const PT* prow = P + (size_t)(t * BATCH + gr) * N3 + gc;
      xc0 = (float)prow[0];        xc1 = (float)prow[1];
      xa0 = (float)prow[HDIM];     xa1 = (float)prow[HDIM + 1];
      xh0 = (float)prow[2 * HDIM]; xh1 = (float)prow[2 * HDIM + 1];
    }

    if (t > 0) {
      if (tid == 0) {
        const u32* cp = cnt + (size_t)t * 64 + rh * 32;   // line-padded per (t, rh)
        while (__hip_atomic_load(cp, __ATOMIC_RELAXED, __HIP_MEMORY_SCOPE_AGENT) < 64u) {
          __builtin_amdgcn_s_sleep(1);
          if (--budget == 0u) break;
        }
      }
      __syncthreads();
    }

    // h fragments: plain cache-bypassing wide loads (sc0 sc1 -> read at coherent point)
    const size_t hb0 = (size_t)(t & 1) * BATCH * HDIM;
    short8 hH[2][4], hL[2][4];
#pragma unroll
    for (int rt = 0; rt < 2; rt++) {
      const u16* pH = Hh + hb0 + (size_t)(r0 + rt * 16 + lr) * HDIM + w * 128 + lk * 8;
      const u16* pL = Hl + hb0 + (size_t)(r0 + rt * 16 + lr) * HDIM + w * 128 + lk * 8;
#pragma unroll
      for (int s = 0; s < 4; s++) {
        asm volatile("global_load_dwordx4 %0, %1, off sc0 sc1"
                     : "=&v"(hH[rt][s]) : "v"(pH + s * 32) : "memory");
        asm volatile("global_load_dwordx4 %0, %1, off sc0 sc1"
                     : "=&v"(hL[rt][s]) : "v"(pL + s * 32) : "memory");
      }
    }
    asm volatile("s_waitcnt vmcnt(0)" ::: "memory");
    __builtin_amdgcn_sched_barrier(0);

    f32x4 acc[2][2];   // [mat][rowtile]
    acc[0][0] = vz; acc[0][1] = vz; acc[1][0] = vz; acc[1][1] = vz;
#pragma unroll
    for (int rt = 0; rt < 2; rt++) {
#pragma unroll
      for (int s = 0; s < 4; s++) {
        acc[0][rt] = __builtin_amdgcn_mfma_f32_16x16x32_bf16(hH[rt][s], bwh[0][s], acc[0][rt], 0, 0, 0);
        acc[0][rt] = __builtin_amdgcn_mfma_f32_16x16x32_bf16(hH[rt][s], bwl[0][s], acc[0][rt], 0, 0, 0);
        acc[0][rt] = __builtin_amdgcn_mfma_f32_16x16x32_bf16(hL[rt][s], bwh[0][s], acc[0][rt], 0, 0, 0);
        acc[1][rt] = __builtin_amdgcn_mfma_f32_16x16x32_bf16(hH[rt][s], bwh[1][s], acc[1][rt], 0, 0, 0);
        acc[1][rt] = __builtin_amdgcn_mfma_f32_16x16x32_bf16(hH[rt][s], bwl[1][s], acc[1][rt], 0, 0, 0);
        acc[1][rt] = __builtin_amdgcn_mfma_f32_16x16x32_bf16(hL[rt][s], bwh[1][s], acc[1][rt], 0, 0, 0);
      }
    }

    // scatter partial pre-activations (D: col=l&15, row=(l>>4)*4+r)
#pragma unroll
    for (int m = 0; m < 2; m++)
#pragma unroll
      for (int rt = 0; rt < 2; rt++)
#pragma unroll
        for (int r = 0; r < 4; r++)
          ex[m][w][rt * 16 + lk * 4 + r][lr] = acc[m][rt][r];
    __syncthreads();

    float hn0 = 0.f, hn1 = 0.f;
    if (tid < 256) {
      const int ec = cq * 2;
      float cp0 = xc0, cp1 = xc1, ap0 = xa0, ap1 = xa1;
#pragma unroll
      for (int q = 0; q < 8; q++) {
        cp0 += ex[0][q][er][ec];     cp1 += ex[0][q][er][ec + 1];
        ap0 += ex[1][q][er][ec];     ap1 += ex[1][q][er][ec + 1];
      }
      float c0g = fsigm(cp0), c1g = fsigm(cp1);
      float aa0 = 1.f + ftanh(ap0), aa1 = 1.f + ftanh(ap1);
      float th0 = ftanh(xh0 + aa0 * hs0), th1 = ftanh(xh1 + aa1 * hs1);
      hn0 = c0g * hs0 + (1.f - c0g) * th0;
      hn1 = c1g * hs1 + (1.f - c1g) * th1;
      hs0 = hn0; hs1 = hn1;

      // h_{t+1} hi/lo bf16 -> IC via agent-scope atomic stores
      u16 hb_0 = f2b(hn0), hb_1 = f2b(hn1);
      u16 lb_0 = f2b(hn0 - bf2f(hb_0)), lb_1 = f2b(hn1 - bf2f(hb_1));
      size_t hidx = ((size_t)((t + 1) & 1) * BATCH * HDIM + (size_t)gr * HDIM + gc) >> 1;
      __hip_atomic_store((u32*)Hh + hidx, (u32)hb_0 | ((u32)hb_1 << 16),
                         __ATOMIC_RELAXED, __HIP_MEMORY_SCOPE_AGENT);
      __hip_atomic_store((u32*)Hl + hidx, (u32)lb_0 | ((u32)lb_1 << 16),
                         __ATOMIC_RELAXED, __HIP_MEMORY_SCOPE_AGENT);
    }

    __syncthreads();   // vmcnt(0) drain: h stores ack'd at coherent point
    if (tid == 0)
      (void)__hip_atomic_fetch_add(cnt + (size_t)(t + 1) * 64 + rh * 32, 1u,
                                   __ATOMIC_RELAXED, __HIP_MEMORY_SCOPE_AGENT);

    // y stores AFTER the release (off the inter-block critical path)
    if (tid < 256) {
      float* yrow = out + (size_t)t * BATCH * HDIM + (size_t)gr * HDIM + gc;
      f32x2 y = {hn0, hn1};
      __builtin_nontemporal_store(y, (f32x2*)yrow);
      if (t == T_STEPS - 1) {
        float* frow = out + (size_t)T_STEPS * BATCH * HDIM + (size_t)gr * HDIM + gc;
        __builtin_nontemporal_store(y, (f32x2*)frow);
      }
    }
  }
}

// ---------------- launcher ----------------
static const size_t SZ_X1 = (size_t)TBm * IDIM * 2;      // 32 MB (hi or lo)
static const size_t SZ_U1 = (size_t)N3 * IDIM * 2;       // 3 MB
static const size_t SZ_W1 = (size_t)2 * HDIM * HDIM * 2; // 4 MB
static const size_t SZ_B  = (size_t)N3 * 4;
static const size_t SZ_H1 = (size_t)2 * BATCH * HDIM * 2;
static const size_t SZ_C  = (size_t)(T_STEPS + 1) * 64 * 4;   // counters, line-padded
static const size_t SZ_TAIL = 2*SZ_X1 + 2*SZ_U1 + 2*SZ_W1 + SZ_B + 2*SZ_H1 + SZ_C;

template<typename PT>
static void launch_path(void* const* d_in, float* out, char* ws, hipStream_t stream) {
  const float* x_seq = (const float*)d_in[0];
  const float* h0   = (const float*)d_in[1];
  const float* U_c  = (const float*)d_in[2];
  const float* W_c  = (const float*)d_in[3];
  const float* b_c  = (const float*)d_in[4];
  const float* U_a  = (const float*)d_in[5];
  const float* W_a  = (const float*)d_in[6];
  const float* b_a  = (const float*)d_in[7];
  const float* U_h  = (const float*)d_in[8];
  const float* b_h  = (const float*)d_in[9];

  const size_t szP = (size_t)TBm * N3 * sizeof(PT);
  PT*  Pb  = (PT*)(ws);
  u16* Xh  = (u16*)(ws + szP);
  u16* Xl  = (u16*)(ws + szP + SZ_X1);
  u16* Uh  = (u16*)(ws + szP + 2*SZ_X1);
  u16* Ul  = (u16*)(ws + szP + 2*SZ_X1 + SZ_U1);
  u16* Wh  = (u16*)(ws + szP + 2*SZ_X1 + 2*SZ_U1);
  u16* Wl  = (u16*)(ws + szP + 2*SZ_X1 + 2*SZ_U1 + SZ_W1);
  float* bias = (float*)(ws + szP + 2*SZ_X1 + 2*SZ_U1 + 2*SZ_W1);
  u16* Hh  = (u16*)((char*)bias + SZ_B);
  u16* Hl  = (u16*)((char*)bias + SZ_B + SZ_H1);
  u32* Cn  = (u32*)((char*)bias + SZ_B + 2*SZ_H1);

  (void)hipMemsetAsync(Cn, 0, SZ_C, stream);
  (void)hipMemcpyAsync(bias + 0 * HDIM, b_c, HDIM * sizeof(float), hipMemcpyDeviceToDevice, stream);
  (void)hipMemcpyAsync(bias + 1 * HDIM, b_a, HDIM * sizeof(float), hipMemcpyDeviceToDevice, stream);
  (void)hipMemcpyAsync(bias + 2 * HDIM, b_h, HDIM * sizeof(float), hipMemcpyDeviceToDevice, stream);

  int n4;
  n4 = TBm * IDIM / 4;
  split_f32<<<(n4 + 255) / 256, 256, 0, stream>>>(x_seq, Xh, Xl, n4);
  n4 = HDIM * IDIM / 4;
  split_f32<<<(n4 + 255) / 256, 256, 0, stream>>>(U_c, Uh + 0 * (size_t)HDIM * IDIM, Ul + 0 * (size_t)HDIM * IDIM, n4);
  split_f32<<<(n4 + 255) / 256, 256, 0, stream>>>(U_a, Uh + 1 * (size_t)HDIM * IDIM, Ul + 1 * (size_t)HDIM * IDIM, n4);
  split_f32<<<(n4 + 255) / 256, 256, 0, stream>>>(U_h, Uh + 2 * (size_t)HDIM * IDIM, Ul + 2 * (size_t)HDIM * IDIM, n4);
  n4 = HDIM * HDIM / 4;
  split_f32<<<(n4 + 255) / 256, 256, 0, stream>>>(W_c, Wh, Wl, n4);
  split_f32<<<(n4 + 255) / 256, 256, 0, stream>>>(W_a, Wh + (size_t)HDIM * HDIM, Wl + (size_t)HDIM * HDIM, n4);
  n4 = BATCH * HDIM / 4;
  split_f32<<<(n4 + 255) / 256, 256, 0, stream>>>(h0, Hh, Hl, n4);

  proj_gemm<PT><<<dim3(TBm / 128, N3 / 128), 256, 0, stream>>>(Xh, Xl, Uh, Ul, bias, Pb);
  scan_kernel<PT><<<NBLK, 512, 0, stream>>>(Pb, Wh, Wl, h0, Hh, Hl, Cn, out);
}

extern "C" void kernel_launch(void* const* d_in, const int* in_sizes, int n_in,
                              void* d_out, int out_size, void* d_ws, size_t ws_size,
                              hipStream_t stream) {
  const size_t need_f32 = (size_t)TBm * N3 * 4 + SZ_TAIL;   // ~463 MB
  const size_t need_f16 = (size_t)TBm * N3 * 2 + SZ_TAIL;   // ~271 MB

  if (ws_size >= need_f32) {
    launch_path<float>(d_in, (float*)d_out, (char*)d_ws, stream);
  } else if (ws_size >= need_f16) {
    launch_path<_Float16>(d_in, (float*)d_out, (char*)d_ws, stream);
  } else {
    float v = 1.0e6f + (float)(ws_size >> 20);   // sentinel: encodes ws MB
    ws_small_kernel<<<2048, 256, 0, stream>>>((float*)d_out, out_size, v);
  }
}

// Round 6
// 2473.242 us; speedup vs baseline: 3.8140x; 1.4231x over previous
//
#include <hip/hip_runtime.h>
#include <stdint.h>

typedef unsigned short u16;
typedef unsigned int u32;
typedef unsigned long long u64;
typedef short short8 __attribute__((ext_vector_type(8)));
typedef float f32x4 __attribute__((ext_vector_type(4)));
typedef float f32x2 __attribute__((ext_vector_type(2)));

#define T_STEPS 512
#define BATCH 64
#define IDIM 512
#define HDIM 1024
#define TBm (T_STEPS*BATCH)      /* 32768 */
#define N3 (3*HDIM)              /* 3072 */
#define NBLK 128                 /* scan blocks: 4 row-groups x 32 col-blocks */

// ---------------- helpers ----------------
__device__ __forceinline__ float bf2f(u16 s) {
  union { u32 u; float f; } v; v.u = ((u32)s) << 16; return v.f;
}
__device__ __forceinline__ u16 f2b(float f) {
  union { float f; u32 u; } v; v.f = f;
  u32 u = v.u;
  u += 0x7fffu + ((u >> 16) & 1u);   // RNE
  return (u16)(u >> 16);
}
__device__ __forceinline__ float ftanh(float x) {
  x = fminf(20.f, fmaxf(-20.f, x));
  float e = __expf(2.f * x);
  return (e - 1.f) / (e + 1.f);
}
__device__ __forceinline__ float fsigm(float x) {
  x = fminf(30.f, fmaxf(-30.f, x));
  return 1.f / (1.f + __expf(-x));
}

// ---------------- f32 -> (bf16 hi, bf16 lo) split, 4 elems/thread ----------------
__global__ void split_f32(const float* __restrict__ src, u16* __restrict__ hi,
                          u16* __restrict__ lo, int n4) {
  int i = blockIdx.x * blockDim.x + threadIdx.x;
  if (i >= n4) return;
  float4 a = ((const float4*)src)[i];
  u16 h0 = f2b(a.x), h1 = f2b(a.y), h2 = f2b(a.z), h3 = f2b(a.w);
  u16 l0 = f2b(a.x - bf2f(h0)), l1 = f2b(a.y - bf2f(h1));
  u16 l2 = f2b(a.z - bf2f(h2)), l3 = f2b(a.w - bf2f(h3));
  uint2 hv; hv.x = (u32)h0 | ((u32)h1 << 16); hv.y = (u32)h2 | ((u32)h3 << 16);
  uint2 lv; lv.x = (u32)l0 | ((u32)l1 << 16); lv.y = (u32)l2 | ((u32)l3 << 16);
  ((uint2*)hi)[i] = hv;
  ((uint2*)lo)[i] = lv;
}

// ---------------- ws-too-small sentinel ----------------
__global__ void ws_small_kernel(float* out, int n, float val) {
  int i = blockIdx.x * blockDim.x + threadIdx.x;
  for (; i < n; i += gridDim.x * blockDim.x) out[i] = val;
}

// ------------- projection GEMM (3-product split): P = Xh@Uh^T + Xh@Ul^T + Xl@Uh^T + b -------------
template<typename PT>
__global__ __launch_bounds__(256) void proj_gemm(const u16* __restrict__ Xh, const u16* __restrict__ Xl,
                                                 const u16* __restrict__ Uh, const u16* __restrict__ Ul,
                                                 const float* __restrict__ bias,
                                                 PT* __restrict__ Pb) {
  __shared__ u16 Ash[4096], Asl[4096], Bsh[4096], Bsl[4096];   // [kc=4][row=128][8]
  const int tid = threadIdx.x;
  const int bm = blockIdx.x, bn = blockIdx.y;
  const int w = tid >> 6, l = tid & 63;
  const int wm = w >> 1, wn = w & 1;
  const int lr = l & 15, kg = l >> 4;

  const int r0t = tid >> 2;           // 0..63
  const int kc = tid & 3;             // k-chunk 0..3
  const size_t ga0 = (size_t)(bm * 128 + r0t) * IDIM + kc * 8;
  const size_t ga1 = ga0 + (size_t)64 * IDIM;
  const size_t gb0 = (size_t)(bn * 128 + r0t) * IDIM + kc * 8;
  const size_t gb1 = gb0 + (size_t)64 * IDIM;
  const int la0 = (kc * 128 + r0t) * 8;
  const int la1 = la0 + 64 * 8;

  uint4 rah0 = *(const uint4*)(Xh + ga0);
  uint4 rah1 = *(const uint4*)(Xh + ga1);
  uint4 ral0 = *(const uint4*)(Xl + ga0);
  uint4 ral1 = *(const uint4*)(Xl + ga1);
  uint4 rbh0 = *(const uint4*)(Uh + gb0);
  uint4 rbh1 = *(const uint4*)(Uh + gb1);
  uint4 rbl0 = *(const uint4*)(Ul + gb0);
  uint4 rbl1 = *(const uint4*)(Ul + gb1);

  const f32x4 vz = {0.f, 0.f, 0.f, 0.f};
  f32x4 acc[4][4];
#pragma unroll
  for (int i = 0; i < 4; i++)
#pragma unroll
    for (int j = 0; j < 4; j++) acc[i][j] = vz;

  for (int kt = 0; kt < 16; kt++) {
    *(uint4*)&Ash[la0] = rah0; *(uint4*)&Ash[la1] = rah1;
    *(uint4*)&Asl[la0] = ral0; *(uint4*)&Asl[la1] = ral1;
    *(uint4*)&Bsh[la0] = rbh0; *(uint4*)&Bsh[la1] = rbh1;
    *(uint4*)&Bsl[la0] = rbl0; *(uint4*)&Bsl[la1] = rbl1;
    __syncthreads();
    if (kt < 15) {
      size_t ko = (size_t)(kt + 1) * 32;
      rah0 = *(const uint4*)(Xh + ga0 + ko); rah1 = *(const uint4*)(Xh + ga1 + ko);
      ral0 = *(const uint4*)(Xl + ga0 + ko); ral1 = *(const uint4*)(Xl + ga1 + ko);
      rbh0 = *(const uint4*)(Uh + gb0 + ko); rbh1 = *(const uint4*)(Uh + gb1 + ko);
      rbl0 = *(const uint4*)(Ul + gb0 + ko); rbl1 = *(const uint4*)(Ul + gb1 + ko);
    }
    short8 afh[4], afl[4], bfh[4], bfl[4];
#pragma unroll
    for (int mt = 0; mt < 4; mt++) {
      int idx = (kg * 128 + wm * 64 + mt * 16 + lr) * 8;
      afh[mt] = *(const short8*)&Ash[idx];
      afl[mt] = *(const short8*)&Asl[idx];
    }
#pragma unroll
    for (int nt = 0; nt < 4; nt++) {
      int idx = (kg * 128 + wn * 64 + nt * 16 + lr) * 8;
      bfh[nt] = *(const short8*)&Bsh[idx];
      bfl[nt] = *(const short8*)&Bsl[idx];
    }
#pragma unroll
    for (int mt = 0; mt < 4; mt++)
#pragma unroll
      for (int nt = 0; nt < 4; nt++) {
        acc[mt][nt] = __builtin_amdgcn_mfma_f32_16x16x32_bf16(afh[mt], bfh[nt], acc[mt][nt], 0, 0, 0);
        acc[mt][nt] = __builtin_amdgcn_mfma_f32_16x16x32_bf16(afh[mt], bfl[nt], acc[mt][nt], 0, 0, 0);
        acc[mt][nt] = __builtin_amdgcn_mfma_f32_16x16x32_bf16(afl[mt], bfh[nt], acc[mt][nt], 0, 0, 0);
      }
    __syncthreads();
  }
#pragma unroll
  for (int mt = 0; mt < 4; mt++) {
#pragma unroll
    for (int nt = 0; nt < 4; nt++) {
      int col = bn * 128 + wn * 64 + nt * 16 + lr;
      float bv = bias[col];
#pragma unroll
      for (int r = 0; r < 4; r++) {
        int row = bm * 128 + wm * 64 + mt * 16 + kg * 4 + r;
        Pb[(size_t)row * N3 + col] = (PT)(acc[mt][nt][r] + bv);
      }
    }
  }
}

// ---------------- persistent recurrent scan ----------------
// 128 blocks x 512 thr (8 waves). Block (rg = blk>>5: 16 rows, cb = blk&31: 32 h-cols, BOTH mats).
// Sync: per-producer flag words (no same-address contention) + wave-parallel ballot poll.
// h data: agent-atomic u32 stores (reach IC pre-flag) + plain sc0/sc1 bypass dwordx4 loads.
// Wave w = K-eighth (128 K). W regs/wave: 2 mats x 2 col-tiles x 4 k-tiles x hi/lo = 128 VGPRs.
template<typename PT>
__global__ __launch_bounds__(512, 2) void scan_kernel(const PT* __restrict__ P,
                                                      const u16* __restrict__ Wh,
                                                      const u16* __restrict__ Wl,
                                                      const float* __restrict__ h0,
                                                      u16* __restrict__ Hh, u16* __restrict__ Hl,
                                                      u32* __restrict__ flags,
                                                      float* __restrict__ out) {
  __shared__ float ex[2][8][16][36];   // [mat][kq][row][col pad36 -> 2-way-free]
  const int tid = threadIdx.x;
  const int blk = blockIdx.x;
  const int cb = blk & 31, rg = blk >> 5;
  const int c0 = cb * 32, r0 = rg * 16;
  const int w = tid >> 6, l = tid & 63;   // w = K-eighth
  const int lr = l & 15, lk = l >> 4;

  // W fragments -> VGPRs (128 regs), held across all 512 steps
  short8 bwh[2][2][4], bwl[2][2][4];   // [mat][coltile][ktile]
#pragma unroll
  for (int m = 0; m < 2; m++)
#pragma unroll
    for (int ct = 0; ct < 2; ct++) {
      const size_t woff = ((size_t)m << 20) + (size_t)(c0 + ct * 16 + lr) * HDIM + w * 128 + lk * 8;
#pragma unroll
      for (int s = 0; s < 4; s++) {
        bwh[m][ct][s] = *(const short8*)(Wh + woff + s * 32);
        bwl[m][ct][s] = *(const short8*)(Wl + woff + s * 32);
      }
    }

  // elementwise ownership (tid<256): thread -> (row er of 16, col pair cq of 16); exact f32 state
  const int er = (tid & 255) >> 4;       // 0..15
  const int cq = tid & 15;               // 0..15
  const int gr = r0 + er;
  const int gc = c0 + cq * 2;
  float hs0 = 0.f, hs1 = 0.f;
  if (tid < 256) {
    hs0 = h0[(size_t)gr * HDIM + gc];
    hs1 = h0[(size_t)gr * HDIM + gc + 1];
  }

  const f32x4 vz = {0.f, 0.f, 0.f, 0.f};
  u32 budget = 1u << 20;   // poll budget (anti-hang)

#pragma unroll 1
  for (int t = 0; t < T_STEPS; t++) {
    // prefetch this step's projections (independent of h; overlaps poll)
    float xc0 = 0.f, xc1 = 0.f, xa0 = 0.f, xa1 = 0.f, xh0 = 0.f, xh1 = 0.f;
    if (tid < 256) {
      const PT* prow = P + (size_t)(t * BATCH + gr) * N3 + gc;
      xc0 = (float)prow[0];        xc1 = (float)prow[1];
      xa0 = (float)prow[HDIM];     xa1 = (float)prow[HDIM + 1];
      xh0 = (float)prow[2 * HDIM]; xh1 = (float)prow[2 * HDIM + 1];
    }

    if (t > 0) {
      if (tid < 64) {   // wave 0: parallel poll of all 32 producer flags (dup x2)
        const u32* fp = flags + (size_t)t * 128 + rg * 32 + (tid & 31);
        for (;;) {
          u32 v = __hip_atomic_load(fp, __ATOMIC_RELAXED, __HIP_MEMORY_SCOPE_AGENT);
          if (__all(v != 0u) || budget == 0u) break;
          --budget;
          __builtin_amdgcn_s_sleep(1);
        }
      }
      __syncthreads();
    }

    // h fragments: plain cache-bypassing wide loads (sc0 sc1 -> read at coherent point)
    const size_t hb = (size_t)(t & 1) * BATCH * HDIM + (size_t)(r0 + lr) * HDIM + w * 128 + lk * 8;
    short8 hH[4], hL[4];
#pragma unroll
    for (int s = 0; s < 4; s++) {
      asm volatile("global_load_dwordx4 %0, %1, off sc0 sc1"
                   : "=&v"(hH[s]) : "v"(Hh + hb + s * 32) : "memory");
      asm volatile("global_load_dwordx4 %0, %1, off sc0 sc1"
                   : "=&v"(hL[s]) : "v"(Hl + hb + s * 32) : "memory");
    }
    asm volatile("s_waitcnt vmcnt(0)" ::: "memory");
    __builtin_amdgcn_sched_barrier(0);

    f32x4 acc[2][2];   // [mat][coltile]
    acc[0][0] = vz; acc[0][1] = vz; acc[1][0] = vz; acc[1][1] = vz;
#pragma unroll
    for (int s = 0; s < 4; s++) {
#pragma unroll
      for (int m = 0; m < 2; m++)
#pragma unroll
        for (int ct = 0; ct < 2; ct++) {
          acc[m][ct] = __builtin_amdgcn_mfma_f32_16x16x32_bf16(hH[s], bwh[m][ct][s], acc[m][ct], 0, 0, 0);
          acc[m][ct] = __builtin_amdgcn_mfma_f32_16x16x32_bf16(hH[s], bwl[m][ct][s], acc[m][ct], 0, 0, 0);
          acc[m][ct] = __builtin_amdgcn_mfma_f32_16x16x32_bf16(hL[s], bwh[m][ct][s], acc[m][ct], 0, 0, 0);
        }
    }

    // scatter partial pre-activations (D: col=l&15, row=(l>>4)*4+r)
#pragma unroll
    for (int m = 0; m < 2; m++)
#pragma unroll
      for (int ct = 0; ct < 2; ct++)
#pragma unroll
        for (int r = 0; r < 4; r++)
          ex[m][w][lk * 4 + r][ct * 16 + lr] = acc[m][ct][r];
    __syncthreads();

    float hn0 = 0.f, hn1 = 0.f;
    if (tid < 256) {
      const int ec = cq * 2;
      float cp0 = xc0, cp1 = xc1, ap0 = xa0, ap1 = xa1;
#pragma unroll
      for (int q = 0; q < 8; q++) {
        cp0 += ex[0][q][er][ec];     cp1 += ex[0][q][er][ec + 1];
        ap0 += ex[1][q][er][ec];     ap1 += ex[1][q][er][ec + 1];
      }
      float c0g = fsigm(cp0), c1g = fsigm(cp1);
      float aa0 = 1.f + ftanh(ap0), aa1 = 1.f + ftanh(ap1);
      float th0 = ftanh(xh0 + aa0 * hs0), th1 = ftanh(xh1 + aa1 * hs1);
      hn0 = c0g * hs0 + (1.f - c0g) * th0;
      hn1 = c1g * hs1 + (1.f - c1g) * th1;
      hs0 = hn0; hs1 = hn1;

      // h_{t+1} hi/lo bf16 -> IC via agent-scope atomic stores
      u16 hb_0 = f2b(hn0), hb_1 = f2b(hn1);
      u16 lb_0 = f2b(hn0 - bf2f(hb_0)), lb_1 = f2b(hn1 - bf2f(hb_1));
      size_t hidx = ((size_t)((t + 1) & 1) * BATCH * HDIM + (size_t)gr * HDIM + gc) >> 1;
      __hip_atomic_store((u32*)Hh + hidx, (u32)hb_0 | ((u32)hb_1 << 16),
                         __ATOMIC_RELAXED, __HIP_MEMORY_SCOPE_AGENT);
      __hip_atomic_store((u32*)Hl + hidx, (u32)lb_0 | ((u32)lb_1 << 16),
                         __ATOMIC_RELAXED, __HIP_MEMORY_SCOPE_AGENT);
    }

    __syncthreads();   // vmcnt(0) drain per wave: h stores ack'd at coherent point
    if (tid == 0)
      __hip_atomic_store(flags + (size_t)(t + 1) * 128 + rg * 32 + cb, 1u,
                         __ATOMIC_RELAXED, __HIP_MEMORY_SCOPE_AGENT);

    // y stores AFTER the release (off the inter-block critical path)
    if (tid < 256) {
      float* yrow = out + (size_t)t * BATCH * HDIM + (size_t)gr * HDIM + gc;
      f32x2 y = {hn0, hn1};
      __builtin_nontemporal_store(y, (f32x2*)yrow);
      if (t == T_STEPS - 1) {
        float* frow = out + (size_t)T_STEPS * BATCH * HDIM + (size_t)gr * HDIM + gc;
        __builtin_nontemporal_store(y, (f32x2*)frow);
      }
    }
  }
}

// ---------------- launcher ----------------
static const size_t SZ_X1 = (size_t)TBm * IDIM * 2;      // 32 MB (hi or lo)
static const size_t SZ_U1 = (size_t)N3 * IDIM * 2;       // 3 MB
static const size_t SZ_W1 = (size_t)2 * HDIM * HDIM * 2; // 4 MB
static const size_t SZ_B  = (size_t)N3 * 4;
static const size_t SZ_H1 = (size_t)2 * BATCH * HDIM * 2;
static const size_t SZ_C  = (size_t)(T_STEPS + 1) * 128 * 4;   // per-producer flags
static const size_t SZ_TAIL = 2*SZ_X1 + 2*SZ_U1 + 2*SZ_W1 + SZ_B + 2*SZ_H1 + SZ_C;

template<typename PT>
static void launch_path(void* const* d_in, float* out, char* ws, hipStream_t stream) {
  const float* x_seq = (const float*)d_in[0];
  const float* h0   = (const float*)d_in[1];
  const float* U_c  = (const float*)d_in[2];
  const float* W_c  = (const float*)d_in[3];
  const float* b_c  = (const float*)d_in[4];
  const float* U_a  = (const float*)d_in[5];
  const float* W_a  = (const float*)d_in[6];
  const float* b_a  = (const float*)d_in[7];
  const float* U_h  = (const float*)d_in[8];
  const float* b_h  = (const float*)d_in[9];

  const size_t szP = (size_t)TBm * N3 * sizeof(PT);
  PT*  Pb  = (PT*)(ws);
  u16* Xh  = (u16*)(ws + szP);
  u16* Xl  = (u16*)(ws + szP + SZ_X1);
  u16* Uh  = (u16*)(ws + szP + 2*SZ_X1);
  u16* Ul  = (u16*)(ws + szP + 2*SZ_X1 + SZ_U1);
  u16* Wh  = (u16*)(ws + szP + 2*SZ_X1 + 2*SZ_U1);
  u16* Wl  = (u16*)(ws + szP + 2*SZ_X1 + 2*SZ_U1 + SZ_W1);
  float* bias = (float*)(ws + szP + 2*SZ_X1 + 2*SZ_U1 + 2*SZ_W1);
  u16* Hh  = (u16*)((char*)bias + SZ_B);
  u16* Hl  = (u16*)((char*)bias + SZ_B + SZ_H1);
  u32* Fl  = (u32*)((char*)bias + SZ_B + 2*SZ_H1);

  (void)hipMemsetAsync(Fl, 0, SZ_C, stream);
  (void)hipMemcpyAsync(bias + 0 * HDIM, b_c, HDIM * sizeof(float), hipMemcpyDeviceToDevice, stream);
  (void)hipMemcpyAsync(bias + 1 * HDIM, b_a, HDIM * sizeof(float), hipMemcpyDeviceToDevice, stream);
  (void)hipMemcpyAsync(bias + 2 * HDIM, b_h, HDIM * sizeof(float), hipMemcpyDeviceToDevice, stream);

  int n4;
  n4 = TBm * IDIM / 4;
  split_f32<<<(n4 + 255) / 256, 256, 0, stream>>>(x_seq, Xh, Xl, n4);
  n4 = HDIM * IDIM / 4;
  split_f32<<<(n4 + 255) / 256, 256, 0, stream>>>(U_c, Uh + 0 * (size_t)HDIM * IDIM, Ul + 0 * (size_t)HDIM * IDIM, n4);
  split_f32<<<(n4 + 255) / 256, 256, 0, stream>>>(U_a, Uh + 1 * (size_t)HDIM * IDIM, Ul + 1 * (size_t)HDIM * IDIM, n4);
  split_f32<<<(n4 + 255) / 256, 256, 0, stream>>>(U_h, Uh + 2 * (size_t)HDIM * IDIM, Ul + 2 * (size_t)HDIM * IDIM, n4);
  n4 = HDIM * HDIM / 4;
  split_f32<<<(n4 + 255) / 256, 256, 0, stream>>>(W_c, Wh, Wl, n4);
  split_f32<<<(n4 + 255) / 256, 256, 0, stream>>>(W_a, Wh + (size_t)HDIM * HDIM, Wl + (size_t)HDIM * HDIM, n4);
  n4 = BATCH * HDIM / 4;
  split_f32<<<(n4 + 255) / 256, 256, 0, stream>>>(h0, Hh, Hl, n4);

  proj_gemm<PT><<<dim3(TBm / 128, N3 / 128), 256, 0, stream>>>(Xh, Xl, Uh, Ul, bias, Pb);
  scan_kernel<PT><<<NBLK, 512, 0, stream>>>(Pb, Wh, Wl, h0, Hh, Hl, Fl, out);
}

extern "C" void kernel_launch(void* const* d_in, const int* in_sizes, int n_in,
                              void* d_out, int out_size, void* d_ws, size_t ws_size,
                              hipStream_t stream) {
  const size_t need_f32 = (size_t)TBm * N3 * 4 + SZ_TAIL;   // ~463 MB
  const size_t need_f16 = (size_t)TBm * N3 * 2 + SZ_TAIL;   // ~271 MB

  if (ws_size >= need_f32) {
    launch_path<float>(d_in, (float*)d_out, (char*)d_ws, stream);
  } else if (ws_size >= need_f16) {
    launch_path<_Float16>(d_in, (float*)d_out, (char*)d_ws, stream);
  } else {
    float v = 1.0e6f + (float)(ws_size >> 20);   // sentinel: encodes ws MB
    ws_small_kernel<<<2048, 256, 0, stream>>>((float*)d_out, out_size, v);
  }
}